// Round 1
// baseline (336.430 us; speedup 1.0000x reference)
//
#include <hip/hip_runtime.h>

// 2D Haar DWT, single fused pass.
// x: (BC, 1024, 1024) fp32 -> out: [LL | LH | HL | HH], each (BC, 512, 512) fp32.
// Per output pixel (i,j):
//   a=x[2i-1,2j-1] b=x[2i-1,2j] c=x[2i,2j-1] d=x[2i,2j]   (index -1 => 0)
//   LL=0.5(a+b+c+d) LH=0.5(c+d-a-b) HL=0.5((b-a)+(d-c)) HH=0.5((d-c)-(b-a))
// Thread t handles 4 consecutive output cols of one output row:
//   needs input cols 8j4-1 .. 8j4+6 of rows 2i-1 and 2i
//   => 2x float4 aligned loads per row + 1 scalar (L1-hit) per row.

__global__ __launch_bounds__(256) void dwt_haar_kernel(
    const float* __restrict__ x, float* __restrict__ out, int n_bc)
{
    constexpr int W  = 1024;   // input width
    constexpr int Ho = 512;    // output height
    constexpr int Wo = 512;    // output width
    constexpr int J4 = Wo / 4; // 128 col-groups per output row

    const long long S = (long long)n_bc * Ho * Wo; // subband size (elements)

    int g   = blockIdx.x * 256 + threadIdx.x;
    int j4  = g & (J4 - 1);        // col group within row
    int rem = g >> 7;              // /J4
    int i   = rem & (Ho - 1);      // output row
    int bc  = rem >> 9;            // image plane

    const float* rbot = x + ((long long)bc * 1024 + 2 * i) * W; // row 2i
    const int c0 = j4 << 3;                                     // input col 8*j4

    float bot[9], top[9];
    {
        float4 v0 = *(const float4*)(rbot + c0);
        float4 v1 = *(const float4*)(rbot + c0 + 4);
        bot[1] = v0.x; bot[2] = v0.y; bot[3] = v0.z; bot[4] = v0.w;
        bot[5] = v1.x; bot[6] = v1.y; bot[7] = v1.z; bot[8] = v1.w;
        bot[0] = (j4 > 0) ? rbot[c0 - 1] : 0.0f;   // col 8*j4-1 (zero-pad at -1)
    }
    if (i > 0) {                                    // row 2i-1 (zero-pad at -1)
        const float* rtop = rbot - W;
        float4 v0 = *(const float4*)(rtop + c0);
        float4 v1 = *(const float4*)(rtop + c0 + 4);
        top[1] = v0.x; top[2] = v0.y; top[3] = v0.z; top[4] = v0.w;
        top[5] = v1.x; top[6] = v1.y; top[7] = v1.z; top[8] = v1.w;
        top[0] = (j4 > 0) ? rtop[c0 - 1] : 0.0f;
    } else {
#pragma unroll
        for (int k = 0; k < 9; ++k) top[k] = 0.0f;
    }

    float llv[4], lhv[4], hlv[4], hhv[4];
#pragma unroll
    for (int k = 0; k < 4; ++k) {
        float a = top[2 * k], b = top[2 * k + 1];
        float c = bot[2 * k], d = bot[2 * k + 1];
        float sum_t = a + b, dif_t = b - a;
        float sum_b = c + d, dif_b = d - c;
        llv[k] = 0.5f * (sum_t + sum_b);
        lhv[k] = 0.5f * (sum_b - sum_t);
        hlv[k] = 0.5f * (dif_t + dif_b);
        hhv[k] = 0.5f * (dif_b - dif_t);
    }

    const long long obase = ((long long)bc * Ho + i) * Wo + (j4 << 2);
    *(float4*)(out +         obase) = make_float4(llv[0], llv[1], llv[2], llv[3]);
    *(float4*)(out +     S + obase) = make_float4(lhv[0], lhv[1], lhv[2], lhv[3]);
    *(float4*)(out + 2 * S + obase) = make_float4(hlv[0], hlv[1], hlv[2], hlv[3]);
    *(float4*)(out + 3 * S + obase) = make_float4(hhv[0], hhv[1], hhv[2], hhv[3]);
}

extern "C" void kernel_launch(void* const* d_in, const int* in_sizes, int n_in,
                              void* d_out, int out_size, void* d_ws, size_t ws_size,
                              hipStream_t stream) {
    const float* x = (const float*)d_in[0];
    float* out = (float*)d_out;

    const int n_bc = in_sizes[0] / (1024 * 1024);          // B*C = 48
    const long long total_threads = (long long)n_bc * 512 * 128; // rows * col-groups
    const int blocks = (int)(total_threads / 256);         // 12288

    dwt_haar_kernel<<<blocks, 256, 0, stream>>>(x, out, n_bc);
}